// Round 6
// baseline (213.339 us; speedup 1.0000x reference)
//
#include <hip/hip_runtime.h>
#include <hip/hip_bf16.h>

typedef unsigned int  uint;
typedef unsigned short ushort;
typedef short bf16x8 __attribute__((ext_vector_type(8)));
typedef float f32x4  __attribute__((ext_vector_type(4)));

#define HW   4096
#define KD   2304   // 9 taps * 256 c

__device__ __forceinline__ void load_lds16(const void* g, void* l) {
    __builtin_amdgcn_global_load_lds((const __attribute__((address_space(1))) void*)g,
                                     (__attribute__((address_space(3))) void*)l, 16, 0, 0);
}
__device__ __forceinline__ float blo(uint u) { return __uint_as_float(u << 16); }
__device__ __forceinline__ float bhi(uint u) { return __uint_as_float(u & 0xffff0000u); }
__device__ __forceinline__ uint pack2(float e, float o) {
    __hip_bfloat16 he = __float2bfloat16(e), ho = __float2bfloat16(o);
    return (uint)(*(ushort*)&he) | ((uint)(*(ushort*)&ho) << 16);
}

// ---- x -> bf16 position-major: x2t[(b*4096 + a)*128 + cp] = {c=2cp, c=2cp+1}
__global__ void prep_x2t(const float* __restrict__ x, uint* __restrict__ x2t) {
    __shared__ uint tl[32][65];
    int bidx = blockIdx.x;              // 4 b * 4 cpb * 64 ab = 1024
    int ab  = bidx & 63;
    int cpb = (bidx >> 6) & 3;
    int b   = bidx >> 8;
    int t = threadIdx.x;                // 256
#pragma unroll
    for (int i = 0; i < 8; ++i) {
        int idx = i * 256 + t;
        int cp = idx >> 6, a = idx & 63;           // cp in [0,32)
        const float* p = x + ((size_t)(b * 256 + (cpb * 32 + cp) * 2)) * HW + ab * 64 + a;
        tl[cp][a] = pack2(p[0], p[HW]);
    }
    __syncthreads();
#pragma unroll
    for (int i = 0; i < 8; ++i) {
        int idx = i * 256 + t;
        int a = idx >> 5, cp = idx & 31;
        x2t[((size_t)b * 4096 + ab * 64 + a) * 128 + cpb * 32 + cp] = tl[cp][a];
    }
}

// ---- w_def -> Bt[o*2304 + tap*256 + c]
__global__ void prep_bt(const float* __restrict__ w_def, ushort* __restrict__ bt) {
    int idx = blockIdx.x * 256 + threadIdx.x;      // 589,824
    int c   = idx & 255;
    int tap = (idx >> 8) % 9;
    int o   = idx / KD;
    __hip_bfloat16 h = __float2bfloat16(w_def[(o * 256 + c) * 9 + tap]);
    bt[idx] = *(ushort*)&h;
}

// ---- w_off -> Bt0[j*2304 + tap*256 + c], rows 18..31 zero
__global__ void prep_bt0(const float* __restrict__ w_off, ushort* __restrict__ bt0) {
    int idx = blockIdx.x * 256 + threadIdx.x;      // 73,728
    int c   = idx & 255;
    int tap = (idx >> 8) % 9;
    int j   = idx / KD;
    float v = (j < 18) ? w_off[(j * 256 + c) * 9 + tap] : 0.f;
    __hip_bfloat16 h = __float2bfloat16(v);
    bt0[idx] = *(ushort*)&h;
}

// ---- fused offset conv: direct implicit GEMM from x2t ----
__global__ __launch_bounds__(512) void gemm_off(const uint* __restrict__ x2t,
                                                const ushort* __restrict__ bt0,
                                                const float* __restrict__ b_off,
                                                float* __restrict__ off) {
    int id = blockIdx.x;
    int xcd = id & 7;
    int b = xcd >> 1, h = (xcd & 1) * 32 + (id >> 3);
    int t = threadIdx.x, wv = t >> 6, lane = t & 63;
    int mrow = lane & 15, quad = lane >> 4;
    int mq = wv & 3, nn = wv >> 2;

    __shared__ uint   lX[3 * 64 * 32];     // [dy][w][cp'] dwords, 24 KB
    __shared__ ushort lB[32 * 576];        // [o][72 chunks of 8, XOR-swizzled], 36 KB

    f32x4 acc = {0.f, 0.f, 0.f, 0.f};

    for (int cb = 0; cb < 4; ++cb) {
#pragma unroll
        for (int s = 0; s < 3; ++s) {      // 24 lX phases over 8 waves
            int q   = s * 8 + wv;
            int dy  = q >> 3;              // wave-uniform
            int y   = h + dy - 1;
            int sub = q & 7;
            int wl  = sub * 8 + (lane >> 3);
            int cps = ((lane & 7) ^ ((lane >> 3) & 7)) * 4;   // pre-swizzled source cp
            if ((unsigned)y < 64u) {
                const uint* src = x2t + ((size_t)(b * 4096 + y * 64 + wl)) * 128 + cb * 32 + cps;
                load_lds16(src, &lX[q * 256]);
            } else {
                uint4 z = {0u, 0u, 0u, 0u};
                *(uint4*)&lX[q * 256 + lane * 4] = z;
            }
        }
#pragma unroll
        for (int s = 0; s < 5; ++s) {      // 36 lB phases over 8 waves (guarded, wave-uniform)
            int q = s * 8 + wv;
            if (q < 36) {
                int e = q * 512 + lane * 8;
                int o  = e / 576;
                int r  = e - o * 576;
                int chp = r >> 3;
                int ch  = chp ^ (o & 7);
                int tap = ch >> 3, k8 = ch & 7;
                const ushort* src = bt0 + (size_t)o * KD + tap * 256 + cb * 64 + k8 * 8;
                load_lds16(src, &lB[q * 512]);
            }
        }
        __syncthreads();

#pragma unroll
        for (int tap = 0; tap < 9; ++tap) {
            int dy = tap / 3, dx = tap % 3;
            int xx = mq * 16 + mrow + dx - 1;
            bool vx = (unsigned)xx < 64u;
            int xc = min(max(xx, 0), 63);
#pragma unroll
            for (int kb = 0; kb < 2; ++kb) {
                int cp0 = kb * 16 + quad * 4;
                uint4 ad = {0u, 0u, 0u, 0u};
                if (vx) ad = *(const uint4*)&lX[dy * 2048 + xc * 32 + (cp0 ^ ((xc & 7) * 4))];
                bf16x8 af = *(bf16x8*)&ad;
                int o = nn * 16 + mrow;
                int chs = (tap * 8 + (((kb * 4 + quad)) ^ (o & 7)));
                bf16x8 bfr = *(const bf16x8*)&lB[o * 576 + chs * 8];
                acc = __builtin_amdgcn_mfma_f32_16x16x32_bf16(af, bfr, acc, 0, 0, 0);
            }
        }
        __syncthreads();
    }
    {
        int o = nn * 16 + mrow;
        float bias = (o < 18) ? b_off[o] : 0.f;
        f32x4 v = acc;
        v.x += bias; v.y += bias; v.z += bias; v.w += bias;
        int wpos = mq * 16 + quad * 4;
        *(f32x4*)(off + ((size_t)(b * 32 + o)) * HW + h * 64 + wpos) = v;
    }
}

// ---- fused gather + main GEMM + BN-stats ----
// Producers (waves 0..7): gather + interp + lA write. Consumers (waves 8..15):
// B fragments straight from global bt into regs (double-buffered) + MFMA.
// Main loop uses RAW s_barrier (no compiler vmcnt(0) drain): every VMEM op has
// a register destination, so dependency-counted waitcnts suffice; only the
// producer's lA ds_writes need an explicit lgkmcnt(0) before the barrier.
// __launch_bounds__(1024,1): lift the 64-VGPR cap that spilled R4/R5
// (WRITE_SIZE 32/175 MB of scratch traffic).
__global__ __launch_bounds__(1024, 1) void fused_main(const uint* __restrict__ x2t,
                                                      const ushort* __restrict__ bt,
                                                      const float* __restrict__ off,
                                                      float* __restrict__ out,
                                                      float* __restrict__ stats) {
    int id = blockIdx.x;                      // 256 blocks
    int xcd = id & 7;
    int b = xcd >> 1, h = (xcd & 1) * 32 + (id >> 3);
    int t = threadIdx.x;
    int wv = t >> 6, lane = t & 63;
    int mrow = lane & 15, quad = lane >> 4;
    bool producer = (wv < 8);
    int ppos = (wv << 3) + (lane >> 3);       // producer position 0..63
    int pc8  = lane & 7;                      // producer 16B chunk (4 cp)
    int wvc  = wv - 8;                        // consumer wave 0..7

    __shared__ int    sAc[4][9][64];          // corner plane offsets, 9 KB
    __shared__ float  sWc[4][9][64];          // corner weights, 9 KB
    __shared__ ushort lA[2][64 * 64];         // 2 x 8 KB

    // ---- per-tile coords for all 9 taps ----
    for (int i = t; i < 576; i += 1024) {
        int tap = i >> 6, ww = i & 63;
        int hw = h * 64 + ww;
        float oy = off[((size_t)(b * 32 + 2 * tap)) * HW + hw];
        float ox = off[((size_t)(b * 32 + 2 * tap + 1)) * HW + hw];
        float py = oy + (float)(tap / 3 + h - 1);
        float px = ox + (float)(tap % 3 + ww - 1);
        float y0f = floorf(py), x0f = floorf(px);
        float wy1 = py - y0f, wx1 = px - x0f;
        float wy0 = 1.f - wy1, wx0 = 1.f - wx1;
        bool vy0 = (y0f >= 0.f) && (y0f <= 63.f);
        bool vy1 = (y0f >= -1.f) && (y0f <= 62.f);
        bool vx0 = (x0f >= 0.f) && (x0f <= 63.f);
        bool vx1 = (x0f >= -1.f) && (x0f <= 62.f);
        int iy0 = min(max((int)y0f, 0), 63),  iy1 = min(max((int)y0f + 1, 0), 63);
        int ix0 = min(max((int)x0f, 0), 63),  ix1 = min(max((int)x0f + 1, 0), 63);
        sAc[0][tap][ww] = iy0 * 64 + ix0;
        sAc[1][tap][ww] = iy0 * 64 + ix1;
        sAc[2][tap][ww] = iy1 * 64 + ix0;
        sAc[3][tap][ww] = iy1 * 64 + ix1;
        sWc[0][tap][ww] = wy0 * wx0 * (float)(vy0 && vx0);
        sWc[1][tap][ww] = wy0 * wx1 * (float)(vy0 && vx1);
        sWc[2][tap][ww] = wy1 * wx0 * (float)(vy1 && vx0);
        sWc[3][tap][ww] = wy1 * wx1 * (float)(vy1 && vx1);
    }
    __syncthreads();

    f32x4 acc[4][2];
#pragma unroll
    for (int m = 0; m < 4; ++m)
#pragma unroll
        for (int n = 0; n < 2; ++n) acc[m][n] = {0.f, 0.f, 0.f, 0.f};

    const uint* xb = x2t + (size_t)b * 4096 * 128;

    // producer: issue the 4 corner gathers for slice sl into reg set g (no wait)
    auto issue_gathers = [&](int sl, uint4 (&g)[4]) {
        int tap = sl >> 2, cb = sl & 3;
        const uint* xp = xb + cb * 32 + pc8 * 4;
        g[0] = *(const uint4*)(xp + (size_t)sAc[0][tap][ppos] * 128);
        g[1] = *(const uint4*)(xp + (size_t)sAc[1][tap][ppos] * 128);
        g[2] = *(const uint4*)(xp + (size_t)sAc[2][tap][ppos] * 128);
        g[3] = *(const uint4*)(xp + (size_t)sAc[3][tap][ppos] * 128);
    };
    // producer: interp + pack + LDS write for slice sl from reg set g
    auto finish = [&](int sl, ushort* lAb, const uint4 (&g)[4]) {
        int tap = sl >> 2;
        float f0 = sWc[0][tap][ppos], f1 = sWc[1][tap][ppos];
        float f2 = sWc[2][tap][ppos], f3 = sWc[3][tap][ppos];
        const uint* c0 = (const uint*)&g[0];
        const uint* c1 = (const uint*)&g[1];
        const uint* c2 = (const uint*)&g[2];
        const uint* c3 = (const uint*)&g[3];
        uint r[4];
#pragma unroll
        for (int j = 0; j < 4; ++j) {
            float ev = f0 * blo(c0[j]) + f1 * blo(c1[j]) + f2 * blo(c2[j]) + f3 * blo(c3[j]);
            float ov = f0 * bhi(c0[j]) + f1 * bhi(c1[j]) + f2 * bhi(c2[j]) + f3 * bhi(c3[j]);
            r[j] = pack2(ev, ov);
        }
        uint4 gg = {r[0], r[1], r[2], r[3]};
        *(uint4*)&lAb[ppos * 64 + ((pc8 ^ (ppos & 7)) * 8)] = gg;
    };
    // consumer: load this wave's B fragments for slice sl from global into regs
    auto loadB = [&](int sl, bf16x8 (&br)[4]) {
        int tap = sl >> 2, cb = sl & 3;
        const ushort* base = bt + tap * 256 + cb * 64 + quad * 8;
#pragma unroll
        for (int kb = 0; kb < 2; ++kb)
#pragma unroll
            for (int n = 0; n < 2; ++n) {
                int r = wvc * 32 + n * 16 + mrow;
                br[kb * 2 + n] = *(const bf16x8*)(base + (size_t)r * KD + kb * 32);
            }
    };
    // consumer: MFMA pass over lA buffer bi with B fragments br
    auto mfma_pass = [&](int bi, const bf16x8 (&br)[4]) {
#pragma unroll
        for (int kb = 0; kb < 2; ++kb) {
            bf16x8 af[4];
#pragma unroll
            for (int m = 0; m < 4; ++m) {
                int r = m * 16 + mrow;
                af[m] = *(const bf16x8*)&lA[bi][r * 64 + (((kb * 4 + quad) ^ (r & 7)) * 8)];
            }
#pragma unroll
            for (int n = 0; n < 2; ++n)
#pragma unroll
                for (int m = 0; m < 4; ++m)
                    acc[m][n] = __builtin_amdgcn_mfma_f32_16x16x32_bf16(af[m], br[kb * 2 + n], acc[m][n], 0, 0, 0);
        }
    };

    uint4 gA[4], gB[4];
    bf16x8 brA[4], brB[4];
    // ---- prologue ----
    if (producer) {
        issue_gathers(0, gA);
        finish(0, lA[0], gA);          // compiler waits on gathers(0) by dep
        issue_gathers(1, gB);
        asm volatile("s_waitcnt lgkmcnt(0)" ::: "memory");   // publish lA[0]
    } else {
        loadB(0, brA);
    }
    __builtin_amdgcn_s_barrier();              // lA[0] ready

    // slice s lives in buf s&1; unrolled x2 so reg sets ping-pong (static idx).
    // Raw barriers: prefetch (gathers s+2, B loads s+1) stays in flight across.
    for (int s = 0; s < 36; s += 2) {
        // interval A: consumers eat lA[0] (slice s); producers build lA[1] (s+1)
        if (producer) {
            if (s + 2 < 36) issue_gathers(s + 2, gA);
            finish(s + 1, lA[1], gB);
            asm volatile("s_waitcnt lgkmcnt(0)" ::: "memory");   // publish lA[1]
        } else {
            loadB(s + 1, brB);
            mfma_pass(0, brA);         // ds_reads drained before barrier (MFMA dep)
        }
        __builtin_amdgcn_s_barrier();          // lA[1] ready; lA[0] free
        // interval B: consumers eat lA[1] (slice s+1); producers build lA[0] (s+2)
        if (producer) {
            if (s + 3 < 36) issue_gathers(s + 3, gB);
            if (s + 2 < 36) {
                finish(s + 2, lA[0], gA);
                asm volatile("s_waitcnt lgkmcnt(0)" ::: "memory");   // publish lA[0]
            }
        } else {
            if (s + 2 < 36) loadB(s + 2, brA);
            mfma_pass(1, brB);
        }
        __builtin_amdgcn_s_barrier();          // lA[0] ready; lA[1] free
    }

    // ---- epilogue (consumers only): store + BN stats ----
    if (!producer) {
#pragma unroll
        for (int n = 0; n < 2; ++n) {
            int o = wvc * 32 + n * 16 + mrow;
            float ss = 0.f, qq = 0.f;
#pragma unroll
            for (int m = 0; m < 4; ++m) {
                int pos = m * 16 + quad * 4;
                f32x4 v = acc[m][n];
                *(f32x4*)(out + ((size_t)(b * 256 + o)) * HW + h * 64 + pos) = v;
                ss += v.x + v.y + v.z + v.w;
                qq += v.x * v.x + v.y * v.y + v.z * v.z + v.w * v.w;
            }
            ss += __shfl_xor(ss, 16); ss += __shfl_xor(ss, 32);
            qq += __shfl_xor(qq, 16); qq += __shfl_xor(qq, 32);
            if (quad == 0) {
                atomicAdd(&stats[o], ss);
                atomicAdd(&stats[512 + o], qq);
            }
        }
    }
}

// ---- BN finalize + apply ----
__global__ void bn_finalize(const float* __restrict__ stats,
                            const float* __restrict__ gamma,
                            float* __restrict__ ms) {
    int o = threadIdx.x;                      // 256
    float S = stats[o], S2 = stats[512 + o];
    float m  = S / 16384.f;
    float var = S2 / 16384.f - m * m;
    ms[o]       = m;
    ms[256 + o] = gamma[o] * rsqrtf(var + 1e-5f);
}

__global__ void bn_apply(float* __restrict__ out,
                         const float* __restrict__ ms,
                         const float* __restrict__ beta) {
    int idx4 = blockIdx.x * 256 + threadIdx.x;   // 1,048,576 float4s
    int o = (idx4 >> 10) & 255;
    float4 v = ((const float4*)out)[idx4];
    float mu = ms[o], sc = ms[256 + o], be = beta[o];
    v.x = fmaxf((v.x - mu) * sc + be, 0.f);
    v.y = fmaxf((v.y - mu) * sc + be, 0.f);
    v.z = fmaxf((v.z - mu) * sc + be, 0.f);
    v.w = fmaxf((v.w - mu) * sc + be, 0.f);
    ((float4*)out)[idx4] = v;
}

extern "C" void kernel_launch(void* const* d_in, const int* in_sizes, int n_in,
                              void* d_out, int out_size, void* d_ws, size_t ws_size,
                              hipStream_t stream) {
    const float* x     = (const float*)d_in[0];
    const float* w_off = (const float*)d_in[1];
    const float* b_off = (const float*)d_in[2];
    const float* w_def = (const float*)d_in[3];
    const float* gamma = (const float*)d_in[4];
    const float* beta  = (const float*)d_in[5];
    float* out = (float*)d_out;

    char* ws = (char*)d_ws;
    uint*   x2t   = (uint*)ws;                          // 8,388,608 B
    ushort* bt    = (ushort*)(ws + 8388608);            // 1,179,648 B
    ushort* bt0   = (ushort*)(ws + 9568256);            // 147,456 B
    float*  off   = (float*)(ws + 9715712);             // 2,097,152 B
    float*  stats = (float*)(ws + 11812864);            // 4,096 B
    float*  ms    = (float*)(ws + 11816960);            // 2,048 B

    hipMemsetAsync(stats, 0, 4096, stream);
    prep_x2t<<<1024, 256, 0, stream>>>(x, x2t);
    prep_bt <<<2304, 256, 0, stream>>>(w_def, bt);
    prep_bt0<<<288,  256, 0, stream>>>(w_off, bt0);
    gemm_off<<<256, 512, 0, stream>>>(x2t, bt0, b_off, off);
    fused_main<<<256, 1024, 0, stream>>>(x2t, bt, off, out, stats);
    bn_finalize<<<1, 256, 0, stream>>>(stats, gamma, ms);
    bn_apply<<<4096, 256, 0, stream>>>(out, ms, beta);
}

// Round 7
// 155.837 us; speedup vs baseline: 1.3690x; 1.3690x over previous
//
#include <hip/hip_runtime.h>
#include <hip/hip_bf16.h>

typedef unsigned int  uint;
typedef unsigned short ushort;
typedef short bf16x8 __attribute__((ext_vector_type(8)));
typedef float f32x4  __attribute__((ext_vector_type(4)));

#define HW   4096
#define KD   2304   // 9 taps * 256 c

__device__ __forceinline__ void load_lds16(const void* g, void* l) {
    __builtin_amdgcn_global_load_lds((const __attribute__((address_space(1))) void*)g,
                                     (__attribute__((address_space(3))) void*)l, 16, 0, 0);
}
__device__ __forceinline__ float blo(uint u) { return __uint_as_float(u << 16); }
__device__ __forceinline__ float bhi(uint u) { return __uint_as_float(u & 0xffff0000u); }
__device__ __forceinline__ uint pack2(float e, float o) {
    __hip_bfloat16 he = __float2bfloat16(e), ho = __float2bfloat16(o);
    return (uint)(*(ushort*)&he) | ((uint)(*(ushort*)&ho) << 16);
}

// ---- x -> bf16 position-major: x2t[(b*4096 + a)*128 + cp] = {c=2cp, c=2cp+1}
__global__ void prep_x2t(const float* __restrict__ x, uint* __restrict__ x2t) {
    __shared__ uint tl[32][65];
    int bidx = blockIdx.x;              // 4 b * 4 cpb * 64 ab = 1024
    int ab  = bidx & 63;
    int cpb = (bidx >> 6) & 3;
    int b   = bidx >> 8;
    int t = threadIdx.x;                // 256
#pragma unroll
    for (int i = 0; i < 8; ++i) {
        int idx = i * 256 + t;
        int cp = idx >> 6, a = idx & 63;           // cp in [0,32)
        const float* p = x + ((size_t)(b * 256 + (cpb * 32 + cp) * 2)) * HW + ab * 64 + a;
        tl[cp][a] = pack2(p[0], p[HW]);
    }
    __syncthreads();
#pragma unroll
    for (int i = 0; i < 8; ++i) {
        int idx = i * 256 + t;
        int a = idx >> 5, cp = idx & 31;
        x2t[((size_t)b * 4096 + ab * 64 + a) * 128 + cpb * 32 + cp] = tl[cp][a];
    }
}

// ---- w_def -> Bt[o*2304 + tap*256 + c]
__global__ void prep_bt(const float* __restrict__ w_def, ushort* __restrict__ bt) {
    int idx = blockIdx.x * 256 + threadIdx.x;      // 589,824
    int c   = idx & 255;
    int tap = (idx >> 8) % 9;
    int o   = idx / KD;
    __hip_bfloat16 h = __float2bfloat16(w_def[(o * 256 + c) * 9 + tap]);
    bt[idx] = *(ushort*)&h;
}

// ---- w_off -> Bt0[j*2304 + tap*256 + c], rows 18..31 zero
__global__ void prep_bt0(const float* __restrict__ w_off, ushort* __restrict__ bt0) {
    int idx = blockIdx.x * 256 + threadIdx.x;      // 73,728
    int c   = idx & 255;
    int tap = (idx >> 8) % 9;
    int j   = idx / KD;
    float v = (j < 18) ? w_off[(j * 256 + c) * 9 + tap] : 0.f;
    __hip_bfloat16 h = __float2bfloat16(v);
    bt0[idx] = *(ushort*)&h;
}

// ---- fused offset conv: direct implicit GEMM from x2t ----
__global__ __launch_bounds__(512) void gemm_off(const uint* __restrict__ x2t,
                                                const ushort* __restrict__ bt0,
                                                const float* __restrict__ b_off,
                                                float* __restrict__ off) {
    int id = blockIdx.x;
    int xcd = id & 7;
    int b = xcd >> 1, h = (xcd & 1) * 32 + (id >> 3);
    int t = threadIdx.x, wv = t >> 6, lane = t & 63;
    int mrow = lane & 15, quad = lane >> 4;
    int mq = wv & 3, nn = wv >> 2;

    __shared__ uint   lX[3 * 64 * 32];     // [dy][w][cp'] dwords, 24 KB
    __shared__ ushort lB[32 * 576];        // [o][72 chunks of 8, XOR-swizzled], 36 KB

    f32x4 acc = {0.f, 0.f, 0.f, 0.f};

    for (int cb = 0; cb < 4; ++cb) {
#pragma unroll
        for (int s = 0; s < 3; ++s) {      // 24 lX phases over 8 waves
            int q   = s * 8 + wv;
            int dy  = q >> 3;              // wave-uniform
            int y   = h + dy - 1;
            int sub = q & 7;
            int wl  = sub * 8 + (lane >> 3);
            int cps = ((lane & 7) ^ ((lane >> 3) & 7)) * 4;   // pre-swizzled source cp
            if ((unsigned)y < 64u) {
                const uint* src = x2t + ((size_t)(b * 4096 + y * 64 + wl)) * 128 + cb * 32 + cps;
                load_lds16(src, &lX[q * 256]);
            } else {
                uint4 z = {0u, 0u, 0u, 0u};
                *(uint4*)&lX[q * 256 + lane * 4] = z;
            }
        }
#pragma unroll
        for (int s = 0; s < 5; ++s) {      // 36 lB phases over 8 waves (guarded, wave-uniform)
            int q = s * 8 + wv;
            if (q < 36) {
                int e = q * 512 + lane * 8;
                int o  = e / 576;
                int r  = e - o * 576;
                int chp = r >> 3;
                int ch  = chp ^ (o & 7);
                int tap = ch >> 3, k8 = ch & 7;
                const ushort* src = bt0 + (size_t)o * KD + tap * 256 + cb * 64 + k8 * 8;
                load_lds16(src, &lB[q * 512]);
            }
        }
        __syncthreads();

#pragma unroll
        for (int tap = 0; tap < 9; ++tap) {
            int dy = tap / 3, dx = tap % 3;
            int xx = mq * 16 + mrow + dx - 1;
            bool vx = (unsigned)xx < 64u;
            int xc = min(max(xx, 0), 63);
#pragma unroll
            for (int kb = 0; kb < 2; ++kb) {
                int cp0 = kb * 16 + quad * 4;
                uint4 ad = {0u, 0u, 0u, 0u};
                if (vx) ad = *(const uint4*)&lX[dy * 2048 + xc * 32 + (cp0 ^ ((xc & 7) * 4))];
                bf16x8 af = *(bf16x8*)&ad;
                int o = nn * 16 + mrow;
                int chs = (tap * 8 + (((kb * 4 + quad)) ^ (o & 7)));
                bf16x8 bfr = *(const bf16x8*)&lB[o * 576 + chs * 8];
                acc = __builtin_amdgcn_mfma_f32_16x16x32_bf16(af, bfr, acc, 0, 0, 0);
            }
        }
        __syncthreads();
    }
    {
        int o = nn * 16 + mrow;
        float bias = (o < 18) ? b_off[o] : 0.f;
        f32x4 v = acc;
        v.x += bias; v.y += bias; v.z += bias; v.w += bias;
        int wpos = mq * 16 + quad * 4;
        *(f32x4*)(off + ((size_t)(b * 32 + o)) * HW + h * 64 + wpos) = v;
    }
}

// ---- fused gather + main GEMM + BN-stats ----
// P/C split, raw barriers (structure correctness proven in R6). This round:
// (1) amdgpu_waves_per_eu(4,4) pins the allocator at 128 VGPRs — the HIP
//     __launch_bounds__ 2nd arg was ignored (R5/R6: VGPR=64, ~160 MB spill).
// (2) live-set cut to ~105: producer single gather buffer gA (its vmcnt wait
//     is hidden by co-resident consumer waves), consumer keeps brA/brB.
// (3) T5 s_setprio around the MFMA cluster (P/C role-split = its regime).
__global__ __attribute__((amdgpu_waves_per_eu(4, 4))) __launch_bounds__(1024)
void fused_main(const uint* __restrict__ x2t,
                const ushort* __restrict__ bt,
                const float* __restrict__ off,
                float* __restrict__ out,
                float* __restrict__ stats) {
    int id = blockIdx.x;                      // 256 blocks
    int xcd = id & 7;
    int b = xcd >> 1, h = (xcd & 1) * 32 + (id >> 3);
    int t = threadIdx.x;
    int wv = t >> 6, lane = t & 63;
    int mrow = lane & 15, quad = lane >> 4;
    bool producer = (wv < 8);
    int ppos = (wv << 3) + (lane >> 3);       // producer position 0..63
    int pc8  = lane & 7;                      // producer 16B chunk (4 cp)
    int wvc  = wv - 8;                        // consumer wave 0..7

    __shared__ int    sAc[4][9][64];          // corner plane offsets, 9 KB
    __shared__ float  sWc[4][9][64];          // corner weights, 9 KB
    __shared__ ushort lA[2][64 * 64];         // 2 x 8 KB

    // ---- per-tile coords for all 9 taps ----
    for (int i = t; i < 576; i += 1024) {
        int tap = i >> 6, ww = i & 63;
        int hw = h * 64 + ww;
        float oy = off[((size_t)(b * 32 + 2 * tap)) * HW + hw];
        float ox = off[((size_t)(b * 32 + 2 * tap + 1)) * HW + hw];
        float py = oy + (float)(tap / 3 + h - 1);
        float px = ox + (float)(tap % 3 + ww - 1);
        float y0f = floorf(py), x0f = floorf(px);
        float wy1 = py - y0f, wx1 = px - x0f;
        float wy0 = 1.f - wy1, wx0 = 1.f - wx1;
        bool vy0 = (y0f >= 0.f) && (y0f <= 63.f);
        bool vy1 = (y0f >= -1.f) && (y0f <= 62.f);
        bool vx0 = (x0f >= 0.f) && (x0f <= 63.f);
        bool vx1 = (x0f >= -1.f) && (x0f <= 62.f);
        int iy0 = min(max((int)y0f, 0), 63),  iy1 = min(max((int)y0f + 1, 0), 63);
        int ix0 = min(max((int)x0f, 0), 63),  ix1 = min(max((int)x0f + 1, 0), 63);
        sAc[0][tap][ww] = iy0 * 64 + ix0;
        sAc[1][tap][ww] = iy0 * 64 + ix1;
        sAc[2][tap][ww] = iy1 * 64 + ix0;
        sAc[3][tap][ww] = iy1 * 64 + ix1;
        sWc[0][tap][ww] = wy0 * wx0 * (float)(vy0 && vx0);
        sWc[1][tap][ww] = wy0 * wx1 * (float)(vy0 && vx1);
        sWc[2][tap][ww] = wy1 * wx0 * (float)(vy1 && vx0);
        sWc[3][tap][ww] = wy1 * wx1 * (float)(vy1 && vx1);
    }
    __syncthreads();

    f32x4 acc[4][2];
#pragma unroll
    for (int m = 0; m < 4; ++m)
#pragma unroll
        for (int n = 0; n < 2; ++n) acc[m][n] = {0.f, 0.f, 0.f, 0.f};

    const uint* xb = x2t + (size_t)b * 4096 * 128;

    // producer: issue the 4 corner gathers for slice sl into reg set g (no wait)
    auto issue_gathers = [&](int sl, uint4 (&g)[4]) {
        int tap = sl >> 2, cb = sl & 3;
        const uint* xp = xb + cb * 32 + pc8 * 4;
        g[0] = *(const uint4*)(xp + (size_t)sAc[0][tap][ppos] * 128);
        g[1] = *(const uint4*)(xp + (size_t)sAc[1][tap][ppos] * 128);
        g[2] = *(const uint4*)(xp + (size_t)sAc[2][tap][ppos] * 128);
        g[3] = *(const uint4*)(xp + (size_t)sAc[3][tap][ppos] * 128);
    };
    // producer: interp + pack + LDS write for slice sl from reg set g
    auto finish = [&](int sl, ushort* lAb, const uint4 (&g)[4]) {
        int tap = sl >> 2;
        float f0 = sWc[0][tap][ppos], f1 = sWc[1][tap][ppos];
        float f2 = sWc[2][tap][ppos], f3 = sWc[3][tap][ppos];
        const uint* c0 = (const uint*)&g[0];
        const uint* c1 = (const uint*)&g[1];
        const uint* c2 = (const uint*)&g[2];
        const uint* c3 = (const uint*)&g[3];
        uint r[4];
#pragma unroll
        for (int j = 0; j < 4; ++j) {
            float ev = f0 * blo(c0[j]) + f1 * blo(c1[j]) + f2 * blo(c2[j]) + f3 * blo(c3[j]);
            float ov = f0 * bhi(c0[j]) + f1 * bhi(c1[j]) + f2 * bhi(c2[j]) + f3 * bhi(c3[j]);
            r[j] = pack2(ev, ov);
        }
        uint4 gg = {r[0], r[1], r[2], r[3]};
        *(uint4*)&lAb[ppos * 64 + ((pc8 ^ (ppos & 7)) * 8)] = gg;
    };
    // consumer: load this wave's B fragments for slice sl from global into regs
    auto loadB = [&](int sl, bf16x8 (&br)[4]) {
        int tap = sl >> 2, cb = sl & 3;
        const ushort* base = bt + tap * 256 + cb * 64 + quad * 8;
#pragma unroll
        for (int kb = 0; kb < 2; ++kb)
#pragma unroll
            for (int n = 0; n < 2; ++n) {
                int r = wvc * 32 + n * 16 + mrow;
                br[kb * 2 + n] = *(const bf16x8*)(base + (size_t)r * KD + kb * 32);
            }
    };
    // consumer: MFMA pass over lA buffer bi with B fragments br
    auto mfma_pass = [&](int bi, const bf16x8 (&br)[4]) {
#pragma unroll
        for (int kb = 0; kb < 2; ++kb) {
            bf16x8 af[4];
#pragma unroll
            for (int m = 0; m < 4; ++m) {
                int r = m * 16 + mrow;
                af[m] = *(const bf16x8*)&lA[bi][r * 64 + (((kb * 4 + quad) ^ (r & 7)) * 8)];
            }
#pragma unroll
            for (int n = 0; n < 2; ++n)
#pragma unroll
                for (int m = 0; m < 4; ++m)
                    acc[m][n] = __builtin_amdgcn_mfma_f32_16x16x32_bf16(af[m], br[kb * 2 + n], acc[m][n], 0, 0, 0);
        }
    };

    uint4 gA[4];
    bf16x8 brA[4], brB[4];
    // ---- prologue ----
    if (producer) {
        issue_gathers(0, gA);
        finish(0, lA[0], gA);          // compiler waits on gathers(0) by dep
        asm volatile("s_waitcnt lgkmcnt(0)" ::: "memory");   // publish lA[0]
    } else {
        loadB(0, brA);
        loadB(1, brB);
    }
    __builtin_amdgcn_s_barrier();              // lA[0] ready
    __builtin_amdgcn_sched_barrier(0);

    // slice s in lA[s&1]; raw barriers keep B prefetch in flight across them.
    for (int s = 0; s < 36; s += 2) {
        // interval A: consume slice s (lA[0], brA); produce slice s+1 -> lA[1]
        if (producer) {
            issue_gathers(s + 1, gA);
            finish(s + 1, lA[1], gA);  // vmcnt wait hidden by consumer waves
            asm volatile("s_waitcnt lgkmcnt(0)" ::: "memory");   // publish lA[1]
        } else {
            __builtin_amdgcn_s_setprio(1);
            mfma_pass(0, brA);
            __builtin_amdgcn_s_setprio(0);
            if (s + 2 < 36) loadB(s + 2, brA);   // lands 2 barriers later
        }
        __builtin_amdgcn_s_barrier();          // lA[1] ready; lA[0] free
        __builtin_amdgcn_sched_barrier(0);
        // interval B: consume slice s+1 (lA[1], brB); produce slice s+2 -> lA[0]
        if (producer) {
            if (s + 2 < 36) {
                issue_gathers(s + 2, gA);
                finish(s + 2, lA[0], gA);
                asm volatile("s_waitcnt lgkmcnt(0)" ::: "memory");   // publish lA[0]
            }
        } else {
            __builtin_amdgcn_s_setprio(1);
            mfma_pass(1, brB);
            __builtin_amdgcn_s_setprio(0);
            if (s + 3 < 36) loadB(s + 3, brB);
        }
        __builtin_amdgcn_s_barrier();          // lA[0] ready; lA[1] free
        __builtin_amdgcn_sched_barrier(0);
    }

    // ---- epilogue (consumers only): store + BN stats ----
    if (!producer) {
#pragma unroll
        for (int n = 0; n < 2; ++n) {
            int o = wvc * 32 + n * 16 + mrow;
            float ss = 0.f, qq = 0.f;
#pragma unroll
            for (int m = 0; m < 4; ++m) {
                int pos = m * 16 + quad * 4;
                f32x4 v = acc[m][n];
                *(f32x4*)(out + ((size_t)(b * 256 + o)) * HW + h * 64 + pos) = v;
                ss += v.x + v.y + v.z + v.w;
                qq += v.x * v.x + v.y * v.y + v.z * v.z + v.w * v.w;
            }
            ss += __shfl_xor(ss, 16); ss += __shfl_xor(ss, 32);
            qq += __shfl_xor(qq, 16); qq += __shfl_xor(qq, 32);
            if (quad == 0) {
                atomicAdd(&stats[o], ss);
                atomicAdd(&stats[512 + o], qq);
            }
        }
    }
}

// ---- BN finalize + apply ----
__global__ void bn_finalize(const float* __restrict__ stats,
                            const float* __restrict__ gamma,
                            float* __restrict__ ms) {
    int o = threadIdx.x;                      // 256
    float S = stats[o], S2 = stats[512 + o];
    float m  = S / 16384.f;
    float var = S2 / 16384.f - m * m;
    ms[o]       = m;
    ms[256 + o] = gamma[o] * rsqrtf(var + 1e-5f);
}

__global__ void bn_apply(float* __restrict__ out,
                         const float* __restrict__ ms,
                         const float* __restrict__ beta) {
    int idx4 = blockIdx.x * 256 + threadIdx.x;   // 1,048,576 float4s
    int o = (idx4 >> 10) & 255;
    float4 v = ((const float4*)out)[idx4];
    float mu = ms[o], sc = ms[256 + o], be = beta[o];
    v.x = fmaxf((v.x - mu) * sc + be, 0.f);
    v.y = fmaxf((v.y - mu) * sc + be, 0.f);
    v.z = fmaxf((v.z - mu) * sc + be, 0.f);
    v.w = fmaxf((v.w - mu) * sc + be, 0.f);
    ((float4*)out)[idx4] = v;
}

extern "C" void kernel_launch(void* const* d_in, const int* in_sizes, int n_in,
                              void* d_out, int out_size, void* d_ws, size_t ws_size,
                              hipStream_t stream) {
    const float* x     = (const float*)d_in[0];
    const float* w_off = (const float*)d_in[1];
    const float* b_off = (const float*)d_in[2];
    const float* w_def = (const float*)d_in[3];
    const float* gamma = (const float*)d_in[4];
    const float* beta  = (const float*)d_in[5];
    float* out = (float*)d_out;

    char* ws = (char*)d_ws;
    uint*   x2t   = (uint*)ws;                          // 8,388,608 B
    ushort* bt    = (ushort*)(ws + 8388608);            // 1,179,648 B
    ushort* bt0   = (ushort*)(ws + 9568256);            // 147,456 B
    float*  off   = (float*)(ws + 9715712);             // 2,097,152 B
    float*  stats = (float*)(ws + 11812864);            // 4,096 B
    float*  ms    = (float*)(ws + 11816960);            // 2,048 B

    hipMemsetAsync(stats, 0, 4096, stream);
    prep_x2t<<<1024, 256, 0, stream>>>(x, x2t);
    prep_bt <<<2304, 256, 0, stream>>>(w_def, bt);
    prep_bt0<<<288,  256, 0, stream>>>(w_off, bt0);
    gemm_off<<<256, 512, 0, stream>>>(x2t, bt0, b_off, off);
    fused_main<<<256, 1024, 0, stream>>>(x2t, bt, off, out, stats);
    bn_finalize<<<1, 256, 0, stream>>>(stats, gamma, ms);
    bn_apply<<<4096, 256, 0, stream>>>(out, ms, beta);
}